// Round 17
// baseline (109.742 us; speedup 1.0000x reference)
//
#include <hip/hip_runtime.h>
#include <hip/hip_bf16.h>
#include <math.h>

// Averaged Hausdorff distance between two 16384x3 fp32 point sets.
// R16 post-mortem: occupancy lever exhausted (2048 blocks = -3%; all configs
// plateau at 55-60% issue). Remaining levers: instruction count and ws size
// (gap ~0.9us/MB, measured across 132KB/8MB/16.8MB configs).
// R17: packed f32 math. CDNA2+ v_pk_fma_f32 does 2 f32 FMAs/instruction;
// LLVM selects it for v2f32 fmuladd (ext_vector_type(2) mul+add under HIP's
// default contraction). Inner loop: per p per 4 inner pts = 6 pk_fma +
// 2 packed mins ~= 2.25 inst/pair (was 3.5) -> floor 15.5us.
// LDS is SoA (bx/by/bz/sb arrays, 16B aligned) so one broadcast ds_read_b128
// yields 4 consecutive values of one component.
// Geometry: P=8, CHUNK=256, XBLK=8, SPLIT=64 -> 1024 blocks (4/CU), part
// array 8.4MB (saves ~8us of ws overhead vs 16.8MB). 2-stage reduce.

#define NPTS   16384
#define BLK    256
#define P      8                    // outer points per thread
#define CHUNK  256                  // inner points per LDS tile (== BLK)
#define XBLK   (NPTS / (BLK * P))   // 8
#define SPLIT  (NPTS / CHUNK)       // 64
#define NSLICE 4                    // reduce stage-1 slices per dir
#define YSL    (SPLIT / NSLICE)     // 16
#define FLTMAX 3.402823466e+38f

typedef float f32x2 __attribute__((ext_vector_type(2)));

// ---------------- stage 1: pairwise partial mins (packed fma) ----------------

__global__ __launch_bounds__(BLK, 4)
void pair_part_kernel(const float* __restrict__ s1, const float* __restrict__ s2,
                      float* __restrict__ part /* [2][SPLIT][NPTS] */) {
    __shared__ __align__(16) float bxs[CHUNK];
    __shared__ __align__(16) float bys[CHUNK];
    __shared__ __align__(16) float bzs[CHUNK];
    __shared__ __align__(16) float sbs[CHUNK];

    const int tid = threadIdx.x;
    const int x   = blockIdx.x;
    const int y   = blockIdx.y;
    const int dir = blockIdx.z;
    const float* __restrict__ A = dir ? s2 : s1;
    const float* __restrict__ B = dir ? s1 : s2;

    const int obase = x * (BLK * P);
    const int cbase = y * CHUNK;

    // Stage inner tile (SoA). CHUNK == BLK: one point per thread.
    {
        int g = cbase + tid;
        float bx = B[3 * g], by = B[3 * g + 1], bz = B[3 * g + 2];
        bxs[tid] = bx; bys[tid] = by; bzs[tid] = bz;
        sbs[tid] = fmaf(bx, bx, fmaf(by, by, bz * bz));
    }
    __syncthreads();

    f32x2 m2x[P], m2y[P], m2z[P], mn2[P];
    float sa[P];
    #pragma unroll
    for (int p = 0; p < P; ++p) {
        int i = obase + p * BLK + tid;
        float ax = A[3 * i], ay = A[3 * i + 1], az = A[3 * i + 2];
        sa[p]  = fmaf(ax, ax, fmaf(ay, ay, az * az));   // |a|^2
        float nx = -(ax + ax), ny = -(ay + ay), nz = -(az + az);
        m2x[p] = (f32x2){nx, nx}; m2y[p] = (f32x2){ny, ny}; m2z[p] = (f32x2){nz, nz};
        mn2[p] = (f32x2){FLTMAX, FLTMAX};
    }

    // t = -2ax*bx + (-2ay*by + (-2az*bz + |b|^2)) = d^2 - |a|^2, 2 pairs per
    // v_pk_fma_f32. One broadcast ds_read_b128 per component per 4 inner pts.
    for (int j = 0; j < CHUNK; j += 4) {
        float4 vx = *(const float4*)&bxs[j];
        float4 vy = *(const float4*)&bys[j];
        float4 vz = *(const float4*)&bzs[j];
        float4 vw = *(const float4*)&sbs[j];
        f32x2 bx01 = {vx.x, vx.y}, bx23 = {vx.z, vx.w};
        f32x2 by01 = {vy.x, vy.y}, by23 = {vy.z, vy.w};
        f32x2 bz01 = {vz.x, vz.y}, bz23 = {vz.z, vz.w};
        f32x2 sb01 = {vw.x, vw.y}, sb23 = {vw.z, vw.w};
        #pragma unroll
        for (int p = 0; p < P; ++p) {
            f32x2 t01 = m2z[p] * bz01 + sb01;   // contracts to v_pk_fma_f32
            t01 = m2y[p] * by01 + t01;
            t01 = m2x[p] * bx01 + t01;
            f32x2 t23 = m2z[p] * bz23 + sb23;
            t23 = m2y[p] * by23 + t23;
            t23 = m2x[p] * bx23 + t23;
            mn2[p] = __builtin_elementwise_min(mn2[p],
                     __builtin_elementwise_min(t01, t23));
        }
    }

    // Plain coalesced stores of partial min d^2 (clamped >= 0).
    float* dst = part + ((size_t)dir * SPLIT + y) * NPTS + obase;
    #pragma unroll
    for (int p = 0; p < P; ++p) {
        float m = fminf(mn2[p].x, mn2[p].y);
        dst[p * BLK + tid] = fmaxf(sa[p] + m, 0.0f);
    }
}

// ---------------- stage 2a: min over y within a slice ----------------

__global__ __launch_bounds__(BLK)
void reduce_slice_kernel(const float* __restrict__ part, float* __restrict__ part2) {
    const int tid = threadIdx.x;
    const int i   = blockIdx.x * BLK + tid;   // point index (64 blocks)
    const int sl  = blockIdx.y;               // slice 0..NSLICE-1
    const int dir = blockIdx.z;               // 0/1

    const float* rp = part + ((size_t)dir * SPLIT + sl * YSL) * NPTS + i;
    float m = FLTMAX;
    #pragma unroll 8
    for (int y = 0; y < YSL; ++y) m = fminf(m, rp[(size_t)y * NPTS]);

    part2[((size_t)dir * NSLICE + sl) * NPTS + i] = m;
}

// ---------------- stage 2b: final min, sqrt, block sums ----------------

__global__ __launch_bounds__(BLK)
void reduce_final_kernel(const float* __restrict__ part2, double* __restrict__ blocksum) {
    const int tid = threadIdx.x;
    const int i = blockIdx.x * BLK + tid;     // 64 blocks

    float r = FLTMAX, c = FLTMAX;
    #pragma unroll
    for (int sl = 0; sl < NSLICE; ++sl) {
        r = fminf(r, part2[(size_t)sl * NPTS + i]);
        c = fminf(c, part2[((size_t)NSLICE + sl) * NPTS + i]);
    }
    double s = (double)sqrtf(r) + (double)sqrtf(c);
    for (int off = 32; off > 0; off >>= 1) s += __shfl_down(s, off);
    __shared__ double w[4];
    if ((tid & 63) == 0) w[tid >> 6] = s;
    __syncthreads();
    if (tid == 0) blocksum[blockIdx.x] = w[0] + w[1] + w[2] + w[3];
}

__global__ void final_kernel(const double* __restrict__ blocksum, float* __restrict__ out) {
    const int lane = threadIdx.x;             // 64 threads
    double s = blocksum[lane];
    for (int off = 32; off > 0; off >>= 1) s += __shfl_down(s, off);
    if (lane == 0) out[0] = (float)(s / (double)NPTS);
}

// ---------------- fallback path (atomicMin, small ws) ----------------

__global__ __launch_bounds__(BLK)
void fb_init(unsigned int* rowmin, unsigned int* colmin) {
    int i = blockIdx.x * BLK + threadIdx.x;
    if (i < NPTS) { rowmin[i] = 0x7F7FFFFFu; colmin[i] = 0x7F7FFFFFu; }
}

__global__ __launch_bounds__(BLK, 4)
void fb_pair(const float* __restrict__ s1, const float* __restrict__ s2,
             unsigned int* __restrict__ rowmin, unsigned int* __restrict__ colmin) {
    __shared__ float4 tile[CHUNK];
    const int tid = threadIdx.x;
    const int dir = blockIdx.z;
    const float* __restrict__ A = dir ? s2 : s1;
    const float* __restrict__ B = dir ? s1 : s2;
    unsigned int* __restrict__ outmin = dir ? colmin : rowmin;
    const int obase = blockIdx.x * (BLK * P);
    const int cbase = blockIdx.y * CHUNK;

    {
        int g = cbase + tid;
        float bx = B[3 * g], by = B[3 * g + 1], bz = B[3 * g + 2];
        tile[tid] = make_float4(bx, by, bz, fmaf(bx, bx, fmaf(by, by, bz * bz)));
    }
    __syncthreads();

    float m2x[P], m2y[P], m2z[P], sa[P], mn[P];
    #pragma unroll
    for (int p = 0; p < P; ++p) {
        int i = obase + p * BLK + tid;
        float ax = A[3 * i], ay = A[3 * i + 1], az = A[3 * i + 2];
        sa[p]  = fmaf(ax, ax, fmaf(ay, ay, az * az));
        m2x[p] = -(ax + ax); m2y[p] = -(ay + ay); m2z[p] = -(az + az);
        mn[p]  = FLTMAX;
    }
    for (int j = 0; j < CHUNK; j += 4) {
        float4 b0 = tile[j], b1 = tile[j + 1], b2 = tile[j + 2], b3 = tile[j + 3];
        #pragma unroll
        for (int p = 0; p < P; ++p) {
            float t0 = fmaf(m2x[p], b0.x, fmaf(m2y[p], b0.y, fmaf(m2z[p], b0.z, b0.w)));
            float t1 = fmaf(m2x[p], b1.x, fmaf(m2y[p], b1.y, fmaf(m2z[p], b1.z, b1.w)));
            float t2 = fmaf(m2x[p], b2.x, fmaf(m2y[p], b2.y, fmaf(m2z[p], b2.z, b2.w)));
            float t3 = fmaf(m2x[p], b3.x, fmaf(m2y[p], b3.y, fmaf(m2z[p], b3.z, b3.w)));
            float u = fminf(fminf(mn[p], t0), t1);
            mn[p] = fminf(fminf(u, t2), t3);
        }
    }
    #pragma unroll
    for (int p = 0; p < P; ++p) {
        float d2 = fmaxf(sa[p] + mn[p], 0.0f);
        atomicMin(&outmin[obase + p * BLK + tid], __float_as_uint(d2));
    }
}

__global__ __launch_bounds__(BLK)
void fb_reduce(const unsigned int* __restrict__ rowmin, const unsigned int* __restrict__ colmin,
               double* __restrict__ blocksum) {
    const int tid = threadIdx.x;
    const int i = blockIdx.x * BLK + tid;
    double s = (double)sqrtf(__uint_as_float(rowmin[i]))
             + (double)sqrtf(__uint_as_float(colmin[i]));
    for (int off = 32; off > 0; off >>= 1) s += __shfl_down(s, off);
    __shared__ double w[4];
    if ((tid & 63) == 0) w[tid >> 6] = s;
    __syncthreads();
    if (tid == 0) blocksum[blockIdx.x] = w[0] + w[1] + w[2] + w[3];
}

// ---------------- launch ----------------

extern "C" void kernel_launch(void* const* d_in, const int* in_sizes, int n_in,
                              void* d_out, int out_size, void* d_ws, size_t ws_size,
                              hipStream_t stream) {
    const float* s1 = (const float*)d_in[0];
    const float* s2 = (const float*)d_in[1];
    float* out = (float*)d_out;

    const size_t part_elems  = (size_t)2 * SPLIT * NPTS;     // 2M floats = 8.4 MB
    const size_t part2_elems = (size_t)2 * NSLICE * NPTS;    // 512 KB
    const size_t need = (part_elems + part2_elems) * sizeof(float) + 64 * sizeof(double);

    if (ws_size >= need) {
        float* part  = (float*)d_ws;
        float* part2 = part + part_elems;
        double* blocksum = (double*)(part2 + part2_elems);

        dim3 grid(XBLK, SPLIT, 2);                           // 8 x 64 x 2 = 1024
        pair_part_kernel<<<grid, BLK, 0, stream>>>(s1, s2, part);
        reduce_slice_kernel<<<dim3(NPTS / BLK, NSLICE, 2), BLK, 0, stream>>>(part, part2);
        reduce_final_kernel<<<NPTS / BLK, BLK, 0, stream>>>(part2, blocksum);
        final_kernel<<<1, 64, 0, stream>>>(blocksum, out);
    } else {
        unsigned int* rowmin = (unsigned int*)d_ws;
        unsigned int* colmin = rowmin + NPTS;
        double* blocksum = (double*)(colmin + NPTS);

        fb_init<<<NPTS / BLK, BLK, 0, stream>>>(rowmin, colmin);
        dim3 grid(XBLK, SPLIT, 2);
        fb_pair<<<grid, BLK, 0, stream>>>(s1, s2, rowmin, colmin);
        fb_reduce<<<NPTS / BLK, BLK, 0, stream>>>(rowmin, colmin, blocksum);
        final_kernel<<<1, 64, 0, stream>>>(blocksum, out);
    }
}

// Round 18
// 102.019 us; speedup vs baseline: 1.0757x; 1.0757x over previous
//
#include <hip/hip_runtime.h>
#include <hip/hip_bf16.h>
#include <math.h>

// Averaged Hausdorff distance between two 16384x3 fp32 point sets.
// R17 post-mortem: pk_fma form spilled (~40MB scratch traffic, VGPR=64 by
// compiler heuristic regardless of cap) -> 55.3us. Scalar plateau = 44.7us
// at ~58% issue. Remaining lever: MFMA. -2a.b is a 16384^2 GEMM with K=3.
// R18: bf16 hi/lo split GEMM via mfma_f32_16x16x32_bf16.
//   A-row slots(k): [-2ah(3), -2al(3), -2ah(3), -2al(3), 1, 1, 0..0]
//   B-col slots(k): [ bh(3),  bh(3),  bl(3),  bl(3), sh, sl, 0..0]
//   acc = -2(ah+al).(bh+bl) + |b|^2  (error ~3e-5 abs; d error ~3e-4)
//   rowmin d^2 = |a|^2(fp32) + min acc.  4 fmin per 256 pairs vs 14
//   wave-inst scalar. C/D layout (verified): col=lane&15 row=(lane>>4)*4+r;
//   A/B: row(col)=lane&15, k=(lane>>4)*8+e. LDS XOR-swizzle kills the 8-way
//   bank conflict of 64B-row fragment reads.

#define NPTS   16384
#define BLK    256
#define MB     128                  // A-rows per block
#define NB     512                  // B-cols per block
#define XB     (NPTS / MB)          // 128
#define SPLIT  (NPTS / NB)          // 32
#define NSLICE 4
#define YSL    (SPLIT / NSLICE)     // 8
#define FLTMAX 3.402823466e+38f

typedef short bf16x8 __attribute__((ext_vector_type(8)));
typedef float f32x4  __attribute__((ext_vector_type(4)));

__device__ __forceinline__ unsigned short f2b(float v) {   // fp32 -> bf16 RNE
    unsigned int u = __float_as_uint(v);
    return (unsigned short)((u + 0x7FFFu + ((u >> 16) & 1u)) >> 16);
}
__device__ __forceinline__ float b2f(unsigned short s) {
    return __uint_as_float(((unsigned int)s) << 16);
}
__device__ __forceinline__ unsigned int swz(unsigned int o) {  // LDS bank swizzle
    return o ^ (((o >> 6) & 7u) << 4);
}

// ---------------- prep: pack split-bf16 operands ----------------

__device__ __forceinline__
void pack_point(float x, float y, float z,
                unsigned short* __restrict__ Arow, unsigned short* __restrict__ Brow,
                float* __restrict__ sq) {
    unsigned short hx = f2b(x), hy = f2b(y), hz = f2b(z);
    float fhx = b2f(hx), fhy = b2f(hy), fhz = b2f(hz);
    unsigned short lx = f2b(x - fhx), ly = f2b(y - fhy), lz = f2b(z - fhz);
    unsigned short nhx = f2b(-2.0f * fhx), nhy = f2b(-2.0f * fhy), nhz = f2b(-2.0f * fhz);
    unsigned short nlx = f2b(-2.0f * b2f(lx)), nly = f2b(-2.0f * b2f(ly)), nlz = f2b(-2.0f * b2f(lz));
    float s = fmaf(x, x, fmaf(y, y, z * z));
    unsigned short sh = f2b(s), sl = f2b(s - b2f(sh));
    unsigned short one = 0x3F80;   // 1.0 bf16

    unsigned short A[14] = {nhx,nhy,nhz, nlx,nly,nlz, nhx,nhy,nhz, nlx,nly,nlz, one,one};
    unsigned short B[14] = { hx, hy, hz,  hx, hy, hz,  lx, ly, lz,  lx, ly, lz,  sh, sl};
    #pragma unroll
    for (int k = 0; k < 14; ++k) { Arow[k] = A[k]; Brow[k] = B[k]; }
    #pragma unroll
    for (int k = 14; k < 32; ++k) { Arow[k] = 0; Brow[k] = 0; }
    *sq = s;
}

__global__ __launch_bounds__(BLK)
void prep_kernel(const float* __restrict__ s1, const float* __restrict__ s2,
                 unsigned short* __restrict__ pA1, unsigned short* __restrict__ pB1,
                 unsigned short* __restrict__ pA2, unsigned short* __restrict__ pB2,
                 float* __restrict__ sqa1, float* __restrict__ sqa2) {
    int i = blockIdx.x * BLK + threadIdx.x;
    pack_point(s1[3*i], s1[3*i+1], s1[3*i+2], pA1 + (size_t)i*32, pB1 + (size_t)i*32, &sqa1[i]);
    pack_point(s2[3*i], s2[3*i+1], s2[3*i+2], pA2 + (size_t)i*32, pB2 + (size_t)i*32, &sqa2[i]);
}

// ---------------- MFMA pair kernel ----------------

__global__ __launch_bounds__(BLK, 4)
void mfma_pair_kernel(const unsigned short* __restrict__ pA1, const unsigned short* __restrict__ pB1,
                      const unsigned short* __restrict__ pA2, const unsigned short* __restrict__ pB2,
                      float* __restrict__ part /* [2][SPLIT][NPTS] */) {
    __shared__ __align__(16) unsigned char ldsA[MB * 64];   // 8 KB
    __shared__ __align__(16) unsigned char ldsB[NB * 64];   // 32 KB

    const int tid  = threadIdx.x;
    const int lane = tid & 63;
    const int w    = tid >> 6;            // wave 0..3
    const int x    = blockIdx.x;
    const int y    = blockIdx.y;
    const int dir  = blockIdx.z;

    const uint4* Ag = (const uint4*)(dir ? pA2 : pA1);   // rows
    const uint4* Bg = (const uint4*)(dir ? pB1 : pB2);   // cols
    const int obase = x * MB;
    const int cbase = y * NB;

    // Stage A panel (512 uint4) and B panel (2048 uint4), swizzled.
    #pragma unroll
    for (int c = 0; c < 2; ++c) {
        int idx = c * BLK + tid;
        *(uint4*)&ldsA[swz(idx * 16)] = Ag[(size_t)obase * 4 + idx];
    }
    #pragma unroll
    for (int c = 0; c < 8; ++c) {
        int idx = c * BLK + tid;
        *(uint4*)&ldsB[swz(idx * 16)] = Bg[(size_t)cbase * 4 + idx];
    }
    __syncthreads();

    // A fragments for this wave's two 16-row tiles (rows w*32 .. w*32+31).
    const int kg = lane >> 4;             // k-group 0..3 (k = kg*8 + e)
    const int r0 = w * 32 + (lane & 15);
    bf16x8 a0 = *(const bf16x8*)&ldsA[swz((unsigned)(r0       * 64 + kg * 16))];
    bf16x8 a1 = *(const bf16x8*)&ldsA[swz((unsigned)((r0 + 16) * 64 + kg * 16))];

    f32x4 rm0 = {FLTMAX, FLTMAX, FLTMAX, FLTMAX};
    f32x4 rm1 = {FLTMAX, FLTMAX, FLTMAX, FLTMAX};
    const f32x4 z4 = {0.0f, 0.0f, 0.0f, 0.0f};

    #pragma unroll 4
    for (int u = 0; u < NB / 16; ++u) {   // 32 j-tiles
        const int col = u * 16 + (lane & 15);
        bf16x8 bf = *(const bf16x8*)&ldsB[swz((unsigned)(col * 64 + kg * 16))];
        f32x4 c0 = __builtin_amdgcn_mfma_f32_16x16x32_bf16(a0, bf, z4, 0, 0, 0);
        f32x4 c1 = __builtin_amdgcn_mfma_f32_16x16x32_bf16(a1, bf, z4, 0, 0, 0);
        rm0.x = fminf(rm0.x, c0.x); rm0.y = fminf(rm0.y, c0.y);
        rm0.z = fminf(rm0.z, c0.z); rm0.w = fminf(rm0.w, c0.w);
        rm1.x = fminf(rm1.x, c1.x); rm1.y = fminf(rm1.y, c1.y);
        rm1.z = fminf(rm1.z, c1.z); rm1.w = fminf(rm1.w, c1.w);
    }

    // Min across the 16 columns held by lanes sharing kg; C row = kg*4 + r.
    float* base = part + ((size_t)dir * SPLIT + y) * NPTS;
    #pragma unroll
    for (int t = 0; t < 2; ++t) {
        f32x4 rm = t ? rm1 : rm0;
        float v0 = rm.x, v1 = rm.y, v2 = rm.z, v3 = rm.w;
        #pragma unroll
        for (int m = 1; m <= 8; m <<= 1) {
            v0 = fminf(v0, __shfl_xor(v0, m));
            v1 = fminf(v1, __shfl_xor(v1, m));
            v2 = fminf(v2, __shfl_xor(v2, m));
            v3 = fminf(v3, __shfl_xor(v3, m));
        }
        if ((lane & 15) == 0) {
            int row = obase + w * 32 + t * 16 + kg * 4;
            base[row + 0] = v0; base[row + 1] = v1;
            base[row + 2] = v2; base[row + 3] = v3;
        }
    }
}

// ---------------- reduce ----------------

__global__ __launch_bounds__(BLK)
void reduce_slice_kernel(const float* __restrict__ part, float* __restrict__ part2) {
    const int i   = blockIdx.x * BLK + threadIdx.x;
    const int sl  = blockIdx.y;
    const int dir = blockIdx.z;
    const float* rp = part + ((size_t)dir * SPLIT + sl * YSL) * NPTS + i;
    float m = FLTMAX;
    #pragma unroll
    for (int yy = 0; yy < YSL; ++yy) m = fminf(m, rp[(size_t)yy * NPTS]);
    part2[((size_t)dir * NSLICE + sl) * NPTS + i] = m;
}

__global__ __launch_bounds__(BLK)
void reduce_final_kernel(const float* __restrict__ part2,
                         const float* __restrict__ sqa1, const float* __restrict__ sqa2,
                         double* __restrict__ blocksum) {
    const int tid = threadIdx.x;
    const int i = blockIdx.x * BLK + tid;
    float r = FLTMAX, c = FLTMAX;
    #pragma unroll
    for (int sl = 0; sl < NSLICE; ++sl) {
        r = fminf(r, part2[(size_t)sl * NPTS + i]);
        c = fminf(c, part2[((size_t)NSLICE + sl) * NPTS + i]);
    }
    double s = (double)sqrtf(fmaxf(sqa1[i] + r, 0.0f))
             + (double)sqrtf(fmaxf(sqa2[i] + c, 0.0f));
    for (int off = 32; off > 0; off >>= 1) s += __shfl_down(s, off);
    __shared__ double wv[4];
    if ((tid & 63) == 0) wv[tid >> 6] = s;
    __syncthreads();
    if (tid == 0) blocksum[blockIdx.x] = wv[0] + wv[1] + wv[2] + wv[3];
}

__global__ void final_kernel(const double* __restrict__ blocksum, float* __restrict__ out) {
    const int lane = threadIdx.x;     // 64 threads
    double s = blocksum[lane];
    for (int off = 32; off > 0; off >>= 1) s += __shfl_down(s, off);
    if (lane == 0) out[0] = (float)(s / (double)NPTS);
}

// ---------------- fallback (scalar, atomicMin, tiny ws) ----------------

__global__ __launch_bounds__(BLK)
void fb_init(unsigned int* rowmin, unsigned int* colmin) {
    int i = blockIdx.x * BLK + threadIdx.x;
    if (i < NPTS) { rowmin[i] = 0x7F7FFFFFu; colmin[i] = 0x7F7FFFFFu; }
}

#define FB_P 8
#define FB_CHUNK 256
__global__ __launch_bounds__(BLK, 4)
void fb_pair(const float* __restrict__ s1, const float* __restrict__ s2,
             unsigned int* __restrict__ rowmin, unsigned int* __restrict__ colmin) {
    __shared__ float4 tile[FB_CHUNK];
    const int tid = threadIdx.x;
    const int dir = blockIdx.z;
    const float* __restrict__ A = dir ? s2 : s1;
    const float* __restrict__ B = dir ? s1 : s2;
    unsigned int* __restrict__ outmin = dir ? colmin : rowmin;
    const int obase = blockIdx.x * (BLK * FB_P);
    const int cbase = blockIdx.y * FB_CHUNK;
    {
        int g = cbase + tid;
        float bx = B[3*g], by = B[3*g+1], bz = B[3*g+2];
        tile[tid] = make_float4(bx, by, bz, fmaf(bx, bx, fmaf(by, by, bz * bz)));
    }
    __syncthreads();
    float m2x[FB_P], m2y[FB_P], m2z[FB_P], sa[FB_P], mn[FB_P];
    #pragma unroll
    for (int p = 0; p < FB_P; ++p) {
        int i = obase + p * BLK + tid;
        float ax = A[3*i], ay = A[3*i+1], az = A[3*i+2];
        sa[p] = fmaf(ax, ax, fmaf(ay, ay, az * az));
        m2x[p] = -(ax+ax); m2y[p] = -(ay+ay); m2z[p] = -(az+az);
        mn[p] = FLTMAX;
    }
    for (int j = 0; j < FB_CHUNK; j += 4) {
        float4 b0 = tile[j], b1 = tile[j+1], b2 = tile[j+2], b3 = tile[j+3];
        #pragma unroll
        for (int p = 0; p < FB_P; ++p) {
            float t0 = fmaf(m2x[p], b0.x, fmaf(m2y[p], b0.y, fmaf(m2z[p], b0.z, b0.w)));
            float t1 = fmaf(m2x[p], b1.x, fmaf(m2y[p], b1.y, fmaf(m2z[p], b1.z, b1.w)));
            float t2 = fmaf(m2x[p], b2.x, fmaf(m2y[p], b2.y, fmaf(m2z[p], b2.z, b2.w)));
            float t3 = fmaf(m2x[p], b3.x, fmaf(m2y[p], b3.y, fmaf(m2z[p], b3.z, b3.w)));
            float u = fminf(fminf(mn[p], t0), t1);
            mn[p] = fminf(fminf(u, t2), t3);
        }
    }
    #pragma unroll
    for (int p = 0; p < FB_P; ++p)
        atomicMin(&outmin[obase + p * BLK + tid], __float_as_uint(fmaxf(sa[p] + mn[p], 0.0f)));
}

__global__ __launch_bounds__(BLK)
void fb_reduce(const unsigned int* __restrict__ rowmin, const unsigned int* __restrict__ colmin,
               double* __restrict__ blocksum) {
    const int tid = threadIdx.x;
    const int i = blockIdx.x * BLK + tid;
    double s = (double)sqrtf(__uint_as_float(rowmin[i]))
             + (double)sqrtf(__uint_as_float(colmin[i]));
    for (int off = 32; off > 0; off >>= 1) s += __shfl_down(s, off);
    __shared__ double wv[4];
    if ((tid & 63) == 0) wv[tid >> 6] = s;
    __syncthreads();
    if (tid == 0) blocksum[blockIdx.x] = wv[0] + wv[1] + wv[2] + wv[3];
}

// ---------------- launch ----------------

extern "C" void kernel_launch(void* const* d_in, const int* in_sizes, int n_in,
                              void* d_out, int out_size, void* d_ws, size_t ws_size,
                              hipStream_t stream) {
    const float* s1 = (const float*)d_in[0];
    const float* s2 = (const float*)d_in[1];
    float* out = (float*)d_out;

    char* base = (char*)d_ws;
    unsigned short* pA1 = (unsigned short*)base;                 // 1 MB each
    unsigned short* pB1 = pA1 + (size_t)NPTS * 32;
    unsigned short* pA2 = pB1 + (size_t)NPTS * 32;
    unsigned short* pB2 = pA2 + (size_t)NPTS * 32;
    float* sqa1 = (float*)(pB2 + (size_t)NPTS * 32);             // 64 KB each
    float* sqa2 = sqa1 + NPTS;
    float* part  = sqa2 + NPTS;                                  // 4 MB
    float* part2 = part + (size_t)2 * SPLIT * NPTS;              // 512 KB
    double* blocksum = (double*)(part2 + (size_t)2 * NSLICE * NPTS);
    const size_t need = (size_t)(blocksum + 64) - (size_t)base + 64;

    if (ws_size >= need) {
        prep_kernel<<<NPTS / BLK, BLK, 0, stream>>>(s1, s2, pA1, pB1, pA2, pB2, sqa1, sqa2);
        dim3 grid(XB, SPLIT, 2);                                 // 128 x 32 x 2 = 8192
        mfma_pair_kernel<<<grid, BLK, 0, stream>>>(pA1, pB1, pA2, pB2, part);
        reduce_slice_kernel<<<dim3(NPTS / BLK, NSLICE, 2), BLK, 0, stream>>>(part, part2);
        reduce_final_kernel<<<NPTS / BLK, BLK, 0, stream>>>(part2, sqa1, sqa2, blocksum);
        final_kernel<<<1, 64, 0, stream>>>(blocksum, out);
    } else {
        unsigned int* rowmin = (unsigned int*)d_ws;
        unsigned int* colmin = rowmin + NPTS;
        double* bsum = (double*)(colmin + NPTS);
        fb_init<<<NPTS / BLK, BLK, 0, stream>>>(rowmin, colmin);
        dim3 grid(NPTS / (BLK * FB_P), NPTS / FB_CHUNK, 2);
        fb_pair<<<grid, BLK, 0, stream>>>(s1, s2, rowmin, colmin);
        fb_reduce<<<NPTS / BLK, BLK, 0, stream>>>(rowmin, colmin, bsum);
        final_kernel<<<1, 64, 0, stream>>>(bsum, out);
    }
}